// Round 10
// baseline (143.311 us; speedup 1.0000x reference)
//
#include <hip/hip_runtime.h>
#include <hip/hip_bf16.h>

// InfoNCE (n_views=1): loss = mean_i [ LSE_{j!=i}(f_i . f_j / T) - f_i . f_{c_i} / T ].
// R10: revert to R7's single-buffered BK=128 K-loop (R8/R9 explicit pipelining
// both regressed — occupancy / barrier-granularity casualties, matching the
// documented m99-m141 pattern) and switch the MFMA to the MX-scaled
// mfma_scale_f32_16x16x128_f8f6f4 with unit scales: 2x the non-scaled fp8 rate
// (m148: 995 -> 1628 TF on the GEMM ladder), 4x fewer MFMA instructions, same
// LDS traffic. A/B assembled identically, so any lane<->k mapping detail
// cancels in the Gram product; uniform 0x7F7F7F7F scale word = 1.0 per block.

typedef float f32x4 __attribute__((ext_vector_type(4)));
typedef int   i32x4 __attribute__((ext_vector_type(4)));
typedef int   i32x8 __attribute__((ext_vector_type(8)));

#define AS1 __attribute__((address_space(1)))
#define AS3 __attribute__((address_space(3)))

constexpr int NB = 8192;   // batch
constexpr int ND = 512;    // dim
constexpr int NBLK = NB / 4;   // combine blocks (4 rows each)
constexpr float INV_T = 1.0f / 0.07f;
constexpr unsigned SCALE1 = 0x7F7F7F7Fu;   // E8M0 exponent 127 -> 2^0 per block

__device__ inline unsigned short f2bf(float f) {
    union { float f; unsigned int u; } v; v.f = f;
    unsigned int u = v.u;
    u = u + 0x7fffu + ((u >> 16) & 1u);   // round-to-nearest-even
    return (unsigned short)(u >> 16);
}
__device__ inline float bf2f(unsigned short s) {
    union { unsigned int u; float f; } v; v.u = ((unsigned int)s) << 16;
    return v.f;
}

// ------- Kernel 1: normalize rows; write row-major fp8 feats + bf16 feats ---------
__global__ __launch_bounds__(256) void norm_kernel(const float* __restrict__ x,
                                                   unsigned char* __restrict__ feats8,
                                                   unsigned short* __restrict__ featsbf) {
    const int wave = threadIdx.x >> 6;
    const int lane = threadIdx.x & 63;
    const int row  = blockIdx.x * 4 + wave;
    const float4* xr = (const float4*)(x + (size_t)row * ND);
    float4 a = xr[2 * lane];       // cols 8*lane   .. +3
    float4 b = xr[2 * lane + 1];   // cols 8*lane+4 .. +7
    float ss = a.x*a.x + a.y*a.y + a.z*a.z + a.w*a.w
             + b.x*b.x + b.y*b.y + b.z*b.z + b.w*b.w;
    #pragma unroll
    for (int m = 32; m >= 1; m >>= 1) ss += __shfl_xor(ss, m);
    float scale = 1.0f / fmaxf(sqrtf(ss), 1e-12f);
    a.x *= scale; a.y *= scale; a.z *= scale; a.w *= scale;
    b.x *= scale; b.y *= scale; b.z *= scale; b.w *= scale;

    // bf16 copy, row-major — used by combine's target dot
    uint4 ub;
    ub.x = (unsigned)f2bf(a.x) | ((unsigned)f2bf(a.y) << 16);
    ub.y = (unsigned)f2bf(a.z) | ((unsigned)f2bf(a.w) << 16);
    ub.z = (unsigned)f2bf(b.x) | ((unsigned)f2bf(b.y) << 16);
    ub.w = (unsigned)f2bf(b.z) | ((unsigned)f2bf(b.w) << 16);
    ((uint4*)(featsbf + (size_t)row * ND))[lane] = ub;

    // fp8 e4m3, plain row-major (8 bytes per lane)
    int w0 = __builtin_amdgcn_cvt_pk_fp8_f32(a.x, a.y, 0, false);
    w0     = __builtin_amdgcn_cvt_pk_fp8_f32(a.z, a.w, w0, true);
    int w1 = __builtin_amdgcn_cvt_pk_fp8_f32(b.x, b.y, 0, false);
    w1     = __builtin_amdgcn_cvt_pk_fp8_f32(b.z, b.w, w1, true);
    uint2 u8; u8.x = (unsigned)w0; u8.y = (unsigned)w1;
    ((uint2*)(feats8 + (size_t)row * ND))[lane] = u8;
}

// ------- Kernel 2: upper-tri 128x128 tiles, MX-scaled fp8 K=128 MFMA --------------
// 2080 blocks -> (bi <= bj). 4 waves = 2x2 quadrants of 64x64. 4 K-windows of
// 128 B; single-buffered 2x16 KB LDS (R7 structure). Staging: LDS slot c of a
// row holds global 16-B unit (c&7)^(row&7); reader fetches units (2q)^sw and
// (2q+1)^sw as two ds_read_b128 (2-way bank aliasing only -> free).
__global__ __launch_bounds__(256) void sim_lse_kernel(const unsigned char* __restrict__ feats8,
                                                      float* __restrict__ partials) {
    __shared__ unsigned char sA[128 * 128];
    __shared__ unsigned char sB[128 * 128];

    const int tid  = threadIdx.x;
    const int lane = tid & 63;
    const int wave = tid >> 6;
    const int wr   = wave >> 1;     // wave row quadrant (0..1)
    const int wc   = wave & 1;      // wave col quadrant (0..1)

    // decode upper-triangle pair: t -> (bi <= bj)
    int t = blockIdx.x;
    int bj = (int)((sqrtf(8.0f * (float)t + 1.0f) - 1.0f) * 0.5f);
    while ((bj + 1) * (bj + 2) / 2 <= t) ++bj;
    while (bj * (bj + 1) / 2 > t) --bj;
    const int bi = t - bj * (bj + 1) / 2;

    const int rowA0 = bi * 128;
    const int rowB0 = bj * 128;

    f32x4 acc[4][4] = {};

    const int m    = lane & 15;
    const int quad = lane >> 4;
    const int sw   = m & 7;                      // unit swizzle (row & 7 == m & 7)
    const int u0   = ((2 * quad)     ^ sw) << 4; // k-low 16-B unit offset
    const int u1   = ((2 * quad + 1) ^ sw) << 4; // k-high 16-B unit offset

    for (int w = 0; w < 4; ++w) {
        const int k0 = w * 128;       // byte offset of window w in the 512-B row
        #pragma unroll
        for (int r = 0; r < 4; ++r) {
            int c   = r * 256 + tid;  // 16-B chunk id (1024 per array)
            int row = c >> 3;
            int u   = (c & 7) ^ (row & 7);
            const unsigned char* ga = feats8 + (size_t)(rowA0 + row) * ND + k0 + u * 16;
            const unsigned char* gb = feats8 + (size_t)(rowB0 + row) * ND + k0 + u * 16;
            __builtin_amdgcn_global_load_lds((const AS1 void*)ga, (AS3 void*)(sA + c * 16), 16, 0, 0);
            __builtin_amdgcn_global_load_lds((const AS1 void*)gb, (AS3 void*)(sB + c * 16), 16, 0, 0);
        }
        __syncthreads();

        i32x8 afr[4], bfr[4];
        #pragma unroll
        for (int s = 0; s < 4; ++s) {
            const unsigned char* pa = sA + (wr * 64 + s * 16 + m) * 128;
            const unsigned char* pb = sB + (wc * 64 + s * 16 + m) * 128;
            i32x4 alo = *(const i32x4*)(pa + u0);
            i32x4 ahi = *(const i32x4*)(pa + u1);
            i32x4 blo = *(const i32x4*)(pb + u0);
            i32x4 bhi = *(const i32x4*)(pb + u1);
            afr[s] = i32x8{alo[0], alo[1], alo[2], alo[3], ahi[0], ahi[1], ahi[2], ahi[3]};
            bfr[s] = i32x8{blo[0], blo[1], blo[2], blo[3], bhi[0], bhi[1], bhi[2], bhi[3]};
        }
        #pragma unroll
        for (int si = 0; si < 4; ++si)
            #pragma unroll
            for (int sj = 0; sj < 4; ++sj)
                acc[si][sj] = __builtin_amdgcn_mfma_scale_f32_16x16x128_f8f6f4(
                    afr[si], bfr[sj], acc[si][sj],
                    0, 0,                     // cbsz = fp8 e4m3, blgp = fp8 e4m3
                    0, (int)SCALE1,           // scale A: opsel 0, all blocks 2^0
                    0, (int)SCALE1);          // scale B: opsel 0, all blocks 2^0
        if (w < 3) __syncthreads();
    }

    // ---- Transform in place: acc <- exp((sim-1)/T), diagonal -> 0 ----
    // C/D layout (16x16 shape, dtype/FMT-independent): col = lane&15, row = quad*4 + reg.
    const float C1 = INV_T * 1.4426950408889634f;   // log2(e)/T
    #pragma unroll
    for (int si = 0; si < 4; ++si) {
        #pragma unroll
        for (int sj = 0; sj < 4; ++sj) {
            const int gcol = rowB0 + wc * 64 + sj * 16 + m;
            #pragma unroll
            for (int r = 0; r < 4; ++r) {
                const int grow = rowA0 + wr * 64 + si * 16 + quad * 4 + r;
                float e = exp2f(fmaf(acc[si][sj][r], C1, -C1));
                acc[si][sj][r] = (grow == gcol) ? 0.0f : e;
            }
        }
    }

    // ---- Row pass: per-row sumexp over this wave's 64 cols ----
    #pragma unroll
    for (int si = 0; si < 4; ++si) {
        #pragma unroll
        for (int r = 0; r < 4; ++r) {
            float s = acc[si][0][r] + acc[si][1][r] + acc[si][2][r] + acc[si][3][r];
            #pragma unroll
            for (int msk = 1; msk < 16; msk <<= 1) s += __shfl_xor(s, msk);
            if (m == 0) {
                const int grow = rowA0 + wr * 64 + si * 16 + quad * 4 + r;
                partials[(size_t)grow * 128 + bj * 2 + wc] = s;
            }
        }
    }

    // ---- Col pass (off-diagonal tiles only): sim[j][i] = sim[i][j] ----
    if (bi != bj) {
        #pragma unroll
        for (int sj = 0; sj < 4; ++sj) {
            float s = 0.0f;
            #pragma unroll
            for (int si = 0; si < 4; ++si)
                #pragma unroll
                for (int r = 0; r < 4; ++r) s += acc[si][sj][r];
            s += __shfl_xor(s, 16);
            s += __shfl_xor(s, 32);
            if (quad == 0) {
                const int gcol = rowB0 + wc * 64 + sj * 16 + m;
                partials[(size_t)gcol * 128 + bi * 2 + wr] = s;
            }
        }
    }
}

// ------- Kernel 3: combine partials -> per-block loss sums (plain stores, no atomics)
__global__ __launch_bounds__(256) void combine_kernel(const float* __restrict__ partials,
                                                      const unsigned short* __restrict__ featsbf,
                                                      const int* __restrict__ y,
                                                      float* __restrict__ blockSums) {
    __shared__ float red[4];
    const int wave = threadIdx.x >> 6;
    const int lane = threadIdx.x & 63;
    const int row  = blockIdx.x * 4 + wave;

    float L = partials[(size_t)row * 128 + lane] + partials[(size_t)row * 128 + 64 + lane];
    #pragma unroll
    for (int msk = 1; msk < 64; msk <<= 1) L += __shfl_xor(L, msk);
    float lse = INV_T + __logf(L);   // LSE = 1/T + log sum exp(l - 1/T)

    // target column c = y + (y >= row); dot(f_row, f_c) in bf16->fp32
    const int yv = y[row];
    const int c  = yv + (yv >= row ? 1 : 0);
    uint4 av = ((const uint4*)(featsbf + (size_t)row * ND))[lane];
    uint4 bv = ((const uint4*)(featsbf + (size_t)c   * ND))[lane];
    float dot = 0.0f;
    const unsigned int* au = (const unsigned int*)&av;
    const unsigned int* bu = (const unsigned int*)&bv;
    #pragma unroll
    for (int k = 0; k < 4; ++k) {
        dot += bf2f((unsigned short)(au[k] & 0xffffu)) * bf2f((unsigned short)(bu[k] & 0xffffu));
        dot += bf2f((unsigned short)(au[k] >> 16))     * bf2f((unsigned short)(bu[k] >> 16));
    }
    #pragma unroll
    for (int msk = 1; msk < 64; msk <<= 1) dot += __shfl_xor(dot, msk);

    float loss = lse - dot * INV_T;
    if (lane == 0) red[wave] = loss;
    __syncthreads();
    if (threadIdx.x == 0)
        blockSums[blockIdx.x] = red[0] + red[1] + red[2] + red[3];
}

// ------- Kernel 4: single-block final reduce of 2048 block sums; pack output ------
__global__ __launch_bounds__(256) void finish_kernel(const float* __restrict__ blockSums,
                                                     unsigned int* __restrict__ out) {
    __shared__ float red[4];
    const int wave = threadIdx.x >> 6;
    const int lane = threadIdx.x & 63;
    float s = 0.0f;
    #pragma unroll
    for (int k = 0; k < NBLK / 256; ++k) s += blockSums[threadIdx.x + 256 * k];
    #pragma unroll
    for (int msk = 1; msk < 64; msk <<= 1) s += __shfl_xor(s, msk);
    if (lane == 0) red[wave] = s;
    __syncthreads();
    if (threadIdx.x == 0) {
        float v = (red[0] + red[1] + red[2] + red[3]) * (1.0f / (float)NB);
        unsigned int b = f2bf(v);
        out[0] = (b << 16) | b;   // valid read as fp32 OR bf16
    }
}

extern "C" void kernel_launch(void* const* d_in, const int* in_sizes, int n_in,
                              void* d_out, int out_size, void* d_ws, size_t ws_size,
                              hipStream_t stream) {
    const float* x = (const float*)d_in[0];
    const int*   y = (const int*)d_in[1];

    // ws: [0,4M) fp8 feats (row-major); [4M,12M) bf16 feats; [12M,16M) partials; [16M..) blockSums
    unsigned char*  feats8    = (unsigned char*)d_ws;
    unsigned short* featsbf   = (unsigned short*)((char*)d_ws + (size_t)4 * 1024 * 1024);
    float*          partials  = (float*)((char*)d_ws + (size_t)12 * 1024 * 1024);
    float*          blockSums = (float*)((char*)d_ws + (size_t)16 * 1024 * 1024);

    norm_kernel<<<NB / 4, 256, 0, stream>>>(x, feats8, featsbf);
    const int ntiles = (NB / 128) * (NB / 128 + 1) / 2;   // 2080 upper-tri tiles
    sim_lse_kernel<<<ntiles, 256, 0, stream>>>(feats8, partials);
    combine_kernel<<<NBLK, 256, 0, stream>>>(partials, featsbf, y, blockSums);
    finish_kernel<<<1, 256, 0, stream>>>(blockSums, (unsigned int*)d_out);
}

// Round 11
// 110.118 us; speedup vs baseline: 1.3014x; 1.3014x over previous
//
#include <hip/hip_runtime.h>
#include <hip/hip_bf16.h>

// InfoNCE (n_views=1): loss = mean_i [ LSE_{j!=i}(f_i . f_j / T) - f_i . f_{c_i} / T ].
// FP8 (OCP e4m3) upper-triangle MFMA F F^T + fixed-max softmax partials.
// R11 = exact revert to R7, the measured best (110.6 us total; sim < 43.5 us).
// Feats PRE-PERMUTED per 128-B K-window (16-B unit U=ks2*4+q holds quad-q's
// 8-B fragments for k-steps 2ks2, 2ks2+1): LDS reader is one conflict-free
// ds_read_b128 per fragment pair. Single-buffered BK=128, 32 KB LDS, 88 VGPR,
// ~5 blocks/CU. Post-R7 experiments all regressed: R8 dbuf (64 KB LDS ->
// occupancy halved), R9 BK=64 dbuf (8 barriers + conflicts), R10 MX-scaled
// K=128 (VGPR 152 -> occupancy 10%). The m99-m141 plateau: source-level
// pipelining can't beat the implicit wave-level overlap of this structure.

typedef float f32x4 __attribute__((ext_vector_type(4)));
typedef long l2 __attribute__((ext_vector_type(2)));

#define AS1 __attribute__((address_space(1)))
#define AS3 __attribute__((address_space(3)))

constexpr int NB = 8192;   // batch
constexpr int ND = 512;    // dim
constexpr int NBLK = NB / 4;   // combine blocks (4 rows each)
constexpr float INV_T = 1.0f / 0.07f;

__device__ inline unsigned short f2bf(float f) {
    union { float f; unsigned int u; } v; v.f = f;
    unsigned int u = v.u;
    u = u + 0x7fffu + ((u >> 16) & 1u);   // round-to-nearest-even
    return (unsigned short)(u >> 16);
}
__device__ inline float bf2f(unsigned short s) {
    union { unsigned int u; float f; } v; v.u = ((unsigned int)s) << 16;
    return v.f;
}

// ------- Kernel 1: normalize rows; write PERMUTED fp8 feats + row-major bf16 -------
__global__ __launch_bounds__(256) void norm_kernel(const float* __restrict__ x,
                                                   unsigned char* __restrict__ feats8,
                                                   unsigned short* __restrict__ featsbf) {
    const int wave = threadIdx.x >> 6;
    const int lane = threadIdx.x & 63;
    const int row  = blockIdx.x * 4 + wave;
    const float4* xr = (const float4*)(x + (size_t)row * ND);
    float4 a = xr[2 * lane];       // cols 8*lane   .. +3
    float4 b = xr[2 * lane + 1];   // cols 8*lane+4 .. +7
    float ss = a.x*a.x + a.y*a.y + a.z*a.z + a.w*a.w
             + b.x*b.x + b.y*b.y + b.z*b.z + b.w*b.w;
    #pragma unroll
    for (int m = 32; m >= 1; m >>= 1) ss += __shfl_xor(ss, m);
    float scale = 1.0f / fmaxf(sqrtf(ss), 1e-12f);
    a.x *= scale; a.y *= scale; a.z *= scale; a.w *= scale;
    b.x *= scale; b.y *= scale; b.z *= scale; b.w *= scale;

    // bf16 copy, row-major (contiguous 8 shorts per lane) — used by combine's dot
    uint4 ub;
    ub.x = (unsigned)f2bf(a.x) | ((unsigned)f2bf(a.y) << 16);
    ub.y = (unsigned)f2bf(a.z) | ((unsigned)f2bf(a.w) << 16);
    ub.z = (unsigned)f2bf(b.x) | ((unsigned)f2bf(b.y) << 16);
    ub.w = (unsigned)f2bf(b.z) | ((unsigned)f2bf(b.w) << 16);
    ((uint4*)(featsbf + (size_t)row * ND))[lane] = ub;

    // fp8 e4m3, PERMUTED: lane holds original 8-B piece L (k = 8L..8L+7), i.e.
    // kt = L>>4, ks = (L>>2)&3, q = L&3.  New 8-B slot within the row:
    //   slot = kt*16 + (ks2*4 + q)*2 + (ks&1),  ks2 = ks>>1
    int w0 = __builtin_amdgcn_cvt_pk_fp8_f32(a.x, a.y, 0, false);
    w0     = __builtin_amdgcn_cvt_pk_fp8_f32(a.z, a.w, w0, true);
    int w1 = __builtin_amdgcn_cvt_pk_fp8_f32(b.x, b.y, 0, false);
    w1     = __builtin_amdgcn_cvt_pk_fp8_f32(b.z, b.w, w1, true);
    uint2 u8; u8.x = (unsigned)w0; u8.y = (unsigned)w1;
    const int L    = lane;
    const int slot = ((L >> 4) << 4) + ((((L >> 3) & 1) * 4 + (L & 3)) << 1) + ((L >> 2) & 1);
    ((uint2*)(feats8 + (size_t)row * ND))[slot] = u8;
}

// ------- Kernel 2: upper-tri 128x128 tiles, fp8 MFMA, fused fixed-max sumexp -------
// 2080 blocks -> (bi <= bj). 4 waves = 2x2 quadrants of 64x64. BK=128 fp8 bytes.
// LDS(r, u) = G(r, kt, u ^ (r&7)); reader fetches unit (ks2*4+q)^(r&7) as b128:
// low 8 B = k-step 2ks2 fragment, high 8 B = k-step 2ks2+1. Conflict-free.
__global__ __launch_bounds__(256) void sim_lse_kernel(const unsigned char* __restrict__ feats8,
                                                      float* __restrict__ partials) {
    __shared__ unsigned char sA[128 * 128];
    __shared__ unsigned char sB[128 * 128];

    const int tid  = threadIdx.x;
    const int lane = tid & 63;
    const int wave = tid >> 6;
    const int wr   = wave >> 1;     // wave row quadrant (0..1)
    const int wc   = wave & 1;      // wave col quadrant (0..1)

    // decode upper-triangle pair: t -> (bi <= bj)
    int t = blockIdx.x;
    int bj = (int)((sqrtf(8.0f * (float)t + 1.0f) - 1.0f) * 0.5f);
    while ((bj + 1) * (bj + 2) / 2 <= t) ++bj;
    while (bj * (bj + 1) / 2 > t) --bj;
    const int bi = t - bj * (bj + 1) / 2;

    const int rowA0 = bi * 128;
    const int rowB0 = bj * 128;

    f32x4 acc[4][4] = {};

    const int m    = lane & 15;
    const int quad = lane >> 4;
    const int sw   = m & 7;         // unit swizzle (row & 7 == m & 7)

    for (int kt = 0; kt < 4; ++kt) {
        const int k0 = kt * 128;      // byte offset within the 512 B fp8 row
        #pragma unroll
        for (int r = 0; r < 4; ++r) {
            int c   = r * 256 + tid;  // 16B chunk id (1024 per array)
            int row = c >> 3;
            int k8g = (c & 7) ^ (row & 7);
            const unsigned char* ga = feats8 + (size_t)(rowA0 + row) * ND + k0 + k8g * 16;
            const unsigned char* gb = feats8 + (size_t)(rowB0 + row) * ND + k0 + k8g * 16;
            __builtin_amdgcn_global_load_lds((const AS1 void*)ga, (AS3 void*)(sA + c * 16), 16, 0, 0);
            __builtin_amdgcn_global_load_lds((const AS1 void*)gb, (AS3 void*)(sB + c * 16), 16, 0, 0);
        }
        __syncthreads();
        #pragma unroll
        for (int ks2 = 0; ks2 < 2; ++ks2) {
            const int uoff = ((ks2 * 4 + quad) ^ sw) << 4;   // swizzled 16B unit
            l2 afr[4], bfr[4];
            #pragma unroll
            for (int s = 0; s < 4; ++s) {
                afr[s] = *(const l2*)(sA + (wr * 64 + s * 16 + m) * 128 + uoff);
                bfr[s] = *(const l2*)(sB + (wc * 64 + s * 16 + m) * 128 + uoff);
            }
            #pragma unroll
            for (int e = 0; e < 2; ++e)
                #pragma unroll
                for (int si = 0; si < 4; ++si)
                    #pragma unroll
                    for (int sj = 0; sj < 4; ++sj)
                        acc[si][sj] = __builtin_amdgcn_mfma_f32_16x16x32_fp8_fp8(
                            afr[si][e], bfr[sj][e], acc[si][sj], 0, 0, 0);
        }
        __syncthreads();
    }

    // ---- Transform in place: acc <- exp((sim-1)/T), diagonal -> 0 ----
    // C/D layout (16x16x32, dtype-independent): col = lane&15, row = quad*4 + reg.
    const float C1 = INV_T * 1.4426950408889634f;   // log2(e)/T
    #pragma unroll
    for (int si = 0; si < 4; ++si) {
        #pragma unroll
        for (int sj = 0; sj < 4; ++sj) {
            const int gcol = rowB0 + wc * 64 + sj * 16 + m;
            #pragma unroll
            for (int r = 0; r < 4; ++r) {
                const int grow = rowA0 + wr * 64 + si * 16 + quad * 4 + r;
                float e = exp2f(fmaf(acc[si][sj][r], C1, -C1));
                acc[si][sj][r] = (grow == gcol) ? 0.0f : e;
            }
        }
    }

    // ---- Row pass: per-row sumexp over this wave's 64 cols ----
    #pragma unroll
    for (int si = 0; si < 4; ++si) {
        #pragma unroll
        for (int r = 0; r < 4; ++r) {
            float s = acc[si][0][r] + acc[si][1][r] + acc[si][2][r] + acc[si][3][r];
            #pragma unroll
            for (int msk = 1; msk < 16; msk <<= 1) s += __shfl_xor(s, msk);
            if (m == 0) {
                const int grow = rowA0 + wr * 64 + si * 16 + quad * 4 + r;
                partials[(size_t)grow * 128 + bj * 2 + wc] = s;
            }
        }
    }

    // ---- Col pass (off-diagonal tiles only): sim[j][i] = sim[i][j] ----
    if (bi != bj) {
        #pragma unroll
        for (int sj = 0; sj < 4; ++sj) {
            float s = 0.0f;
            #pragma unroll
            for (int si = 0; si < 4; ++si)
                #pragma unroll
                for (int r = 0; r < 4; ++r) s += acc[si][sj][r];
            s += __shfl_xor(s, 16);
            s += __shfl_xor(s, 32);
            if (quad == 0) {
                const int gcol = rowB0 + wc * 64 + sj * 16 + m;
                partials[(size_t)gcol * 128 + bi * 2 + wr] = s;
            }
        }
    }
}

// ------- Kernel 3: combine partials -> per-block loss sums (plain stores, no atomics)
__global__ __launch_bounds__(256) void combine_kernel(const float* __restrict__ partials,
                                                      const unsigned short* __restrict__ featsbf,
                                                      const int* __restrict__ y,
                                                      float* __restrict__ blockSums) {
    __shared__ float red[4];
    const int wave = threadIdx.x >> 6;
    const int lane = threadIdx.x & 63;
    const int row  = blockIdx.x * 4 + wave;

    float L = partials[(size_t)row * 128 + lane] + partials[(size_t)row * 128 + 64 + lane];
    #pragma unroll
    for (int msk = 1; msk < 64; msk <<= 1) L += __shfl_xor(L, msk);
    float lse = INV_T + __logf(L);   // LSE = 1/T + log sum exp(l - 1/T)

    // target column c = y + (y >= row); dot(f_row, f_c) in bf16->fp32
    const int yv = y[row];
    const int c  = yv + (yv >= row ? 1 : 0);
    uint4 av = ((const uint4*)(featsbf + (size_t)row * ND))[lane];
    uint4 bv = ((const uint4*)(featsbf + (size_t)c   * ND))[lane];
    float dot = 0.0f;
    const unsigned int* au = (const unsigned int*)&av;
    const unsigned int* bu = (const unsigned int*)&bv;
    #pragma unroll
    for (int k = 0; k < 4; ++k) {
        dot += bf2f((unsigned short)(au[k] & 0xffffu)) * bf2f((unsigned short)(bu[k] & 0xffffu));
        dot += bf2f((unsigned short)(au[k] >> 16))     * bf2f((unsigned short)(bu[k] >> 16));
    }
    #pragma unroll
    for (int msk = 1; msk < 64; msk <<= 1) dot += __shfl_xor(dot, msk);

    float loss = lse - dot * INV_T;
    if (lane == 0) red[wave] = loss;
    __syncthreads();
    if (threadIdx.x == 0)
        blockSums[blockIdx.x] = red[0] + red[1] + red[2] + red[3];
}

// ------- Kernel 4: single-block final reduce of 2048 block sums; pack output ------
__global__ __launch_bounds__(256) void finish_kernel(const float* __restrict__ blockSums,
                                                     unsigned int* __restrict__ out) {
    __shared__ float red[4];
    const int wave = threadIdx.x >> 6;
    const int lane = threadIdx.x & 63;
    float s = 0.0f;
    #pragma unroll
    for (int k = 0; k < NBLK / 256; ++k) s += blockSums[threadIdx.x + 256 * k];
    #pragma unroll
    for (int msk = 1; msk < 64; msk <<= 1) s += __shfl_xor(s, msk);
    if (lane == 0) red[wave] = s;
    __syncthreads();
    if (threadIdx.x == 0) {
        float v = (red[0] + red[1] + red[2] + red[3]) * (1.0f / (float)NB);
        unsigned int b = f2bf(v);
        out[0] = (b << 16) | b;   // valid read as fp32 OR bf16
    }
}

extern "C" void kernel_launch(void* const* d_in, const int* in_sizes, int n_in,
                              void* d_out, int out_size, void* d_ws, size_t ws_size,
                              hipStream_t stream) {
    const float* x = (const float*)d_in[0];
    const int*   y = (const int*)d_in[1];

    // ws: [0,4M) fp8 feats (permuted); [4M,12M) bf16 feats; [12M,16M) partials; [16M..) blockSums
    unsigned char*  feats8    = (unsigned char*)d_ws;
    unsigned short* featsbf   = (unsigned short*)((char*)d_ws + (size_t)4 * 1024 * 1024);
    float*          partials  = (float*)((char*)d_ws + (size_t)12 * 1024 * 1024);
    float*          blockSums = (float*)((char*)d_ws + (size_t)16 * 1024 * 1024);

    norm_kernel<<<NB / 4, 256, 0, stream>>>(x, feats8, featsbf);
    const int ntiles = (NB / 128) * (NB / 128 + 1) / 2;   // 2080 upper-tri tiles
    sim_lse_kernel<<<ntiles, 256, 0, stream>>>(feats8, partials);
    combine_kernel<<<NBLK, 256, 0, stream>>>(partials, featsbf, y, blockSums);
    finish_kernel<<<1, 256, 0, stream>>>(blockSums, (unsigned int*)d_out);
}

// Round 12
// 107.616 us; speedup vs baseline: 1.3317x; 1.0233x over previous
//
#include <hip/hip_runtime.h>
#include <hip/hip_bf16.h>

// InfoNCE (n_views=1): loss = mean_i [ LSE_{j!=i}(f_i . f_j / T) - f_i . f_{c_i} / T ].
// FP8 (OCP e4m3) upper-triangle MFMA F F^T + fixed-max softmax partials.
// R12 = R7/R11 structure (the measured plateau: single-buffered BK=128, 32 KB
// LDS, permuted fp8 layout, conflict-free b128 reads) + XCD-AWARE TILE
// ASSIGNMENT: t = (blk&7)*260 + (blk>>3) gives each XCD a contiguous range of
// the column-major triangle traversal, so its ~1.4-4.4 MB tile working set
// stays in its private 4 MB L2 (R11 FETCH=37.5 MB ~= every XCD refetching the
// whole 4 MB feats; expect ~24 MB). Pure index remap, zero resource change.

typedef float f32x4 __attribute__((ext_vector_type(4)));
typedef long l2 __attribute__((ext_vector_type(2)));

#define AS1 __attribute__((address_space(1)))
#define AS3 __attribute__((address_space(3)))

constexpr int NB = 8192;   // batch
constexpr int ND = 512;    // dim
constexpr int NBLK = NB / 4;   // combine blocks (4 rows each)
constexpr float INV_T = 1.0f / 0.07f;

__device__ inline unsigned short f2bf(float f) {
    union { float f; unsigned int u; } v; v.f = f;
    unsigned int u = v.u;
    u = u + 0x7fffu + ((u >> 16) & 1u);   // round-to-nearest-even
    return (unsigned short)(u >> 16);
}
__device__ inline float bf2f(unsigned short s) {
    union { unsigned int u; float f; } v; v.u = ((unsigned int)s) << 16;
    return v.f;
}

// ------- Kernel 1: normalize rows; write PERMUTED fp8 feats + row-major bf16 -------
__global__ __launch_bounds__(256) void norm_kernel(const float* __restrict__ x,
                                                   unsigned char* __restrict__ feats8,
                                                   unsigned short* __restrict__ featsbf) {
    const int wave = threadIdx.x >> 6;
    const int lane = threadIdx.x & 63;
    const int row  = blockIdx.x * 4 + wave;
    const float4* xr = (const float4*)(x + (size_t)row * ND);
    float4 a = xr[2 * lane];       // cols 8*lane   .. +3
    float4 b = xr[2 * lane + 1];   // cols 8*lane+4 .. +7
    float ss = a.x*a.x + a.y*a.y + a.z*a.z + a.w*a.w
             + b.x*b.x + b.y*b.y + b.z*b.z + b.w*b.w;
    #pragma unroll
    for (int m = 32; m >= 1; m >>= 1) ss += __shfl_xor(ss, m);
    float scale = 1.0f / fmaxf(sqrtf(ss), 1e-12f);
    a.x *= scale; a.y *= scale; a.z *= scale; a.w *= scale;
    b.x *= scale; b.y *= scale; b.z *= scale; b.w *= scale;

    // bf16 copy, row-major (contiguous 8 shorts per lane) — used by combine's dot
    uint4 ub;
    ub.x = (unsigned)f2bf(a.x) | ((unsigned)f2bf(a.y) << 16);
    ub.y = (unsigned)f2bf(a.z) | ((unsigned)f2bf(a.w) << 16);
    ub.z = (unsigned)f2bf(b.x) | ((unsigned)f2bf(b.y) << 16);
    ub.w = (unsigned)f2bf(b.z) | ((unsigned)f2bf(b.w) << 16);
    ((uint4*)(featsbf + (size_t)row * ND))[lane] = ub;

    // fp8 e4m3, PERMUTED: lane holds original 8-B piece L (k = 8L..8L+7), i.e.
    // kt = L>>4, ks = (L>>2)&3, q = L&3.  New 8-B slot within the row:
    //   slot = kt*16 + (ks2*4 + q)*2 + (ks&1),  ks2 = ks>>1
    int w0 = __builtin_amdgcn_cvt_pk_fp8_f32(a.x, a.y, 0, false);
    w0     = __builtin_amdgcn_cvt_pk_fp8_f32(a.z, a.w, w0, true);
    int w1 = __builtin_amdgcn_cvt_pk_fp8_f32(b.x, b.y, 0, false);
    w1     = __builtin_amdgcn_cvt_pk_fp8_f32(b.z, b.w, w1, true);
    uint2 u8; u8.x = (unsigned)w0; u8.y = (unsigned)w1;
    const int L    = lane;
    const int slot = ((L >> 4) << 4) + ((((L >> 3) & 1) * 4 + (L & 3)) << 1) + ((L >> 2) & 1);
    ((uint2*)(feats8 + (size_t)row * ND))[slot] = u8;
}

// ------- Kernel 2: upper-tri 128x128 tiles, fp8 MFMA, fused fixed-max sumexp -------
// 2080 blocks -> (bi <= bj). 4 waves = 2x2 quadrants of 64x64. BK=128 fp8 bytes.
// LDS(r, u) = G(r, kt, u ^ (r&7)); reader fetches unit (ks2*4+q)^(r&7) as b128:
// low 8 B = k-step 2ks2 fragment, high 8 B = k-step 2ks2+1. Conflict-free.
__global__ __launch_bounds__(256) void sim_lse_kernel(const unsigned char* __restrict__ feats8,
                                                      float* __restrict__ partials) {
    __shared__ unsigned char sA[128 * 128];
    __shared__ unsigned char sB[128 * 128];

    const int tid  = threadIdx.x;
    const int lane = tid & 63;
    const int wave = tid >> 6;
    const int wr   = wave >> 1;     // wave row quadrant (0..1)
    const int wc   = wave & 1;      // wave col quadrant (0..1)

    // XCD-aware assignment: blocks dispatch round-robin over 8 XCDs, so give
    // XCD x the contiguous traversal range [x*260, (x+1)*260) — its tile
    // working set then fits (mostly) in its private 4 MB L2.
    int t = (blockIdx.x & 7) * 260 + (blockIdx.x >> 3);
    // decode upper-triangle pair: t -> (bi <= bj), column-major over bj
    int bj = (int)((sqrtf(8.0f * (float)t + 1.0f) - 1.0f) * 0.5f);
    while ((bj + 1) * (bj + 2) / 2 <= t) ++bj;
    while (bj * (bj + 1) / 2 > t) --bj;
    const int bi = t - bj * (bj + 1) / 2;

    const int rowA0 = bi * 128;
    const int rowB0 = bj * 128;

    f32x4 acc[4][4] = {};

    const int m    = lane & 15;
    const int quad = lane >> 4;
    const int sw   = m & 7;         // unit swizzle (row & 7 == m & 7)

    for (int kt = 0; kt < 4; ++kt) {
        const int k0 = kt * 128;      // byte offset within the 512 B fp8 row
        #pragma unroll
        for (int r = 0; r < 4; ++r) {
            int c   = r * 256 + tid;  // 16B chunk id (1024 per array)
            int row = c >> 3;
            int k8g = (c & 7) ^ (row & 7);
            const unsigned char* ga = feats8 + (size_t)(rowA0 + row) * ND + k0 + k8g * 16;
            const unsigned char* gb = feats8 + (size_t)(rowB0 + row) * ND + k0 + k8g * 16;
            __builtin_amdgcn_global_load_lds((const AS1 void*)ga, (AS3 void*)(sA + c * 16), 16, 0, 0);
            __builtin_amdgcn_global_load_lds((const AS1 void*)gb, (AS3 void*)(sB + c * 16), 16, 0, 0);
        }
        __syncthreads();
        #pragma unroll
        for (int ks2 = 0; ks2 < 2; ++ks2) {
            const int uoff = ((ks2 * 4 + quad) ^ sw) << 4;   // swizzled 16B unit
            l2 afr[4], bfr[4];
            #pragma unroll
            for (int s = 0; s < 4; ++s) {
                afr[s] = *(const l2*)(sA + (wr * 64 + s * 16 + m) * 128 + uoff);
                bfr[s] = *(const l2*)(sB + (wc * 64 + s * 16 + m) * 128 + uoff);
            }
            #pragma unroll
            for (int e = 0; e < 2; ++e)
                #pragma unroll
                for (int si = 0; si < 4; ++si)
                    #pragma unroll
                    for (int sj = 0; sj < 4; ++sj)
                        acc[si][sj] = __builtin_amdgcn_mfma_f32_16x16x32_fp8_fp8(
                            afr[si][e], bfr[sj][e], acc[si][sj], 0, 0, 0);
        }
        __syncthreads();
    }

    // ---- Transform in place: acc <- exp((sim-1)/T), diagonal -> 0 ----
    // C/D layout (16x16x32, dtype-independent): col = lane&15, row = quad*4 + reg.
    const float C1 = INV_T * 1.4426950408889634f;   // log2(e)/T
    #pragma unroll
    for (int si = 0; si < 4; ++si) {
        #pragma unroll
        for (int sj = 0; sj < 4; ++sj) {
            const int gcol = rowB0 + wc * 64 + sj * 16 + m;
            #pragma unroll
            for (int r = 0; r < 4; ++r) {
                const int grow = rowA0 + wr * 64 + si * 16 + quad * 4 + r;
                float e = exp2f(fmaf(acc[si][sj][r], C1, -C1));
                acc[si][sj][r] = (grow == gcol) ? 0.0f : e;
            }
        }
    }

    // ---- Row pass: per-row sumexp over this wave's 64 cols ----
    #pragma unroll
    for (int si = 0; si < 4; ++si) {
        #pragma unroll
        for (int r = 0; r < 4; ++r) {
            float s = acc[si][0][r] + acc[si][1][r] + acc[si][2][r] + acc[si][3][r];
            #pragma unroll
            for (int msk = 1; msk < 16; msk <<= 1) s += __shfl_xor(s, msk);
            if (m == 0) {
                const int grow = rowA0 + wr * 64 + si * 16 + quad * 4 + r;
                partials[(size_t)grow * 128 + bj * 2 + wc] = s;
            }
        }
    }

    // ---- Col pass (off-diagonal tiles only): sim[j][i] = sim[i][j] ----
    if (bi != bj) {
        #pragma unroll
        for (int sj = 0; sj < 4; ++sj) {
            float s = 0.0f;
            #pragma unroll
            for (int si = 0; si < 4; ++si)
                #pragma unroll
                for (int r = 0; r < 4; ++r) s += acc[si][sj][r];
            s += __shfl_xor(s, 16);
            s += __shfl_xor(s, 32);
            if (quad == 0) {
                const int gcol = rowB0 + wc * 64 + sj * 16 + m;
                partials[(size_t)gcol * 128 + bi * 2 + wr] = s;
            }
        }
    }
}

// ------- Kernel 3: combine partials -> per-block loss sums (plain stores, no atomics)
__global__ __launch_bounds__(256) void combine_kernel(const float* __restrict__ partials,
                                                      const unsigned short* __restrict__ featsbf,
                                                      const int* __restrict__ y,
                                                      float* __restrict__ blockSums) {
    __shared__ float red[4];
    const int wave = threadIdx.x >> 6;
    const int lane = threadIdx.x & 63;
    const int row  = blockIdx.x * 4 + wave;

    float L = partials[(size_t)row * 128 + lane] + partials[(size_t)row * 128 + 64 + lane];
    #pragma unroll
    for (int msk = 1; msk < 64; msk <<= 1) L += __shfl_xor(L, msk);
    float lse = INV_T + __logf(L);   // LSE = 1/T + log sum exp(l - 1/T)

    // target column c = y + (y >= row); dot(f_row, f_c) in bf16->fp32
    const int yv = y[row];
    const int c  = yv + (yv >= row ? 1 : 0);
    uint4 av = ((const uint4*)(featsbf + (size_t)row * ND))[lane];
    uint4 bv = ((const uint4*)(featsbf + (size_t)c   * ND))[lane];
    float dot = 0.0f;
    const unsigned int* au = (const unsigned int*)&av;
    const unsigned int* bu = (const unsigned int*)&bv;
    #pragma unroll
    for (int k = 0; k < 4; ++k) {
        dot += bf2f((unsigned short)(au[k] & 0xffffu)) * bf2f((unsigned short)(bu[k] & 0xffffu));
        dot += bf2f((unsigned short)(au[k] >> 16))     * bf2f((unsigned short)(bu[k] >> 16));
    }
    #pragma unroll
    for (int msk = 1; msk < 64; msk <<= 1) dot += __shfl_xor(dot, msk);

    float loss = lse - dot * INV_T;
    if (lane == 0) red[wave] = loss;
    __syncthreads();
    if (threadIdx.x == 0)
        blockSums[blockIdx.x] = red[0] + red[1] + red[2] + red[3];
}

// ------- Kernel 4: single-block final reduce of 2048 block sums; pack output ------
__global__ __launch_bounds__(256) void finish_kernel(const float* __restrict__ blockSums,
                                                     unsigned int* __restrict__ out) {
    __shared__ float red[4];
    const int wave = threadIdx.x >> 6;
    const int lane = threadIdx.x & 63;
    float s = 0.0f;
    #pragma unroll
    for (int k = 0; k < NBLK / 256; ++k) s += blockSums[threadIdx.x + 256 * k];
    #pragma unroll
    for (int msk = 1; msk < 64; msk <<= 1) s += __shfl_xor(s, msk);
    if (lane == 0) red[wave] = s;
    __syncthreads();
    if (threadIdx.x == 0) {
        float v = (red[0] + red[1] + red[2] + red[3]) * (1.0f / (float)NB);
        unsigned int b = f2bf(v);
        out[0] = (b << 16) | b;   // valid read as fp32 OR bf16
    }
}

extern "C" void kernel_launch(void* const* d_in, const int* in_sizes, int n_in,
                              void* d_out, int out_size, void* d_ws, size_t ws_size,
                              hipStream_t stream) {
    const float* x = (const float*)d_in[0];
    const int*   y = (const int*)d_in[1];

    // ws: [0,4M) fp8 feats (permuted); [4M,12M) bf16 feats; [12M,16M) partials; [16M..) blockSums
    unsigned char*  feats8    = (unsigned char*)d_ws;
    unsigned short* featsbf   = (unsigned short*)((char*)d_ws + (size_t)4 * 1024 * 1024);
    float*          partials  = (float*)((char*)d_ws + (size_t)12 * 1024 * 1024);
    float*          blockSums = (float*)((char*)d_ws + (size_t)16 * 1024 * 1024);

    norm_kernel<<<NB / 4, 256, 0, stream>>>(x, feats8, featsbf);
    const int ntiles = (NB / 128) * (NB / 128 + 1) / 2;   // 2080 upper-tri tiles
    sim_lse_kernel<<<ntiles, 256, 0, stream>>>(feats8, partials);
    combine_kernel<<<NBLK, 256, 0, stream>>>(partials, featsbf, y, blockSums);
    finish_kernel<<<1, 256, 0, stream>>>(blockSums, (unsigned int*)d_out);
}